// Round 1
// baseline (316.257 us; speedup 1.0000x reference)
//
// MultiHeadSelfAttention (B=2,S=2048,d=1024,H=16,Dh=64, causal) on MI355X.
// Pipeline: fp32->bf16 cvt -> QKV GEMM (bf16 MFMA, fp32 acc) -> causal flash
// attention (bf16 MFMA QK^T/PV, fp32 online softmax) -> out GEMM + bias (fp32 out).
// GEMM = m97-style 128x128 tile, BK=32, global_load_lds width 16, 4 waves.
// Scratch lives in __device__ globals (~50MB) to avoid ws_size assumptions.

#include <hip/hip_runtime.h>
#include <stdint.h>

typedef __attribute__((ext_vector_type(8))) short bf16x8;   // 8 bf16 = 4 VGPR (MFMA A/B frag)
typedef __attribute__((ext_vector_type(4))) float f32x4;    // MFMA C/D frag
typedef __attribute__((ext_vector_type(4))) unsigned short u16x4;

#define AS1 __attribute__((address_space(1)))
#define AS3 __attribute__((address_space(3)))

// ---- problem constants ----
#define BATCH 2
#define SEQ   2048
#define DMODEL 1024
#define NHEAD 16
#define DHEAD 64
#define QKVLD 3072           // row stride of qkv buffer (3*d_model)
#define MROWS (BATCH*SEQ)    // 4096

// ---- scratch (bf16 stored as short) ----
__device__ short g_xb   [MROWS * DMODEL];        // x in bf16           8 MB
__device__ short g_wqkv [3*DMODEL * DMODEL];     // W_qkv bf16          6 MB
__device__ short g_wout [DMODEL * DMODEL];       // W_out bf16          2 MB
__device__ short g_qkv  [(size_t)MROWS * QKVLD]; // qkv bf16           24 MB
__device__ short g_attno[MROWS * DMODEL];        // attn output bf16    8 MB

__device__ __forceinline__ unsigned short f2bf(float f) {
  union { float f; unsigned u; } v; v.f = f;
  unsigned r = v.u + 0x7FFFu + ((v.u >> 16) & 1u);   // RNE, finite inputs
  return (unsigned short)(r >> 16);
}

// CK-style pattern: generic->AS casts via uintptr (AS3 ptrs are 32-bit; low 32
// bits of a generic LDS address are the LDS offset). Dest is wave-uniform base,
// HW adds lane*16.
__device__ __forceinline__ void gload_lds16(const void* g, void* l) {
  __builtin_amdgcn_global_load_lds((const AS1 void*)(uintptr_t)g,
                                   (AS3 void*)(uint32_t)(uintptr_t)l, 16, 0, 0);
}

// ---------------- fp32 -> bf16 conversion (all three inputs, one kernel) ----
__global__ void cvt3(const float* __restrict__ x, const float* __restrict__ wq,
                     const float* __restrict__ wo) {
  const int N0 = MROWS * DMODEL;        // 4194304
  const int N1 = 3 * DMODEL * DMODEL;   // 3145728
  const int N2 = DMODEL * DMODEL;       // 1048576
  const int total = N0 + N1 + N2;
  int i = (blockIdx.x * blockDim.x + threadIdx.x) * 4;
  const int stride = gridDim.x * blockDim.x * 4;
  for (; i < total; i += stride) {
    const float* src; short* dst; int off;
    if (i < N0)           { src = x;  dst = g_xb;   off = i; }
    else if (i < N0 + N1) { src = wq; dst = g_wqkv; off = i - N0; }
    else                  { src = wo; dst = g_wout; off = i - N0 - N1; }
    float4 v = *reinterpret_cast<const float4*>(src + off);
    u16x4 o = { f2bf(v.x), f2bf(v.y), f2bf(v.z), f2bf(v.w) };
    *reinterpret_cast<u16x4*>(dst + off) = o;
  }
}

// ---------------- GEMM: C[M,N] = A[M,K] * B[N,K]^T  (both bf16, K-contig) ----
// 128x128 tile, BK=32, 4 waves (2x2), each wave 64x64 = 4x4 16x16 frags.
__device__ __forceinline__ void gemm_body(const short* __restrict__ A,
                                          const short* __restrict__ B,
                                          short* __restrict__ Cb,   // bf16 out (or null)
                                          float* __restrict__ Cf,   // fp32 out (or null)
                                          const float* __restrict__ bias,
                                          int N, int K) {
  __shared__ short As[128 * 32];
  __shared__ short Bs[128 * 32];
  const int tid  = threadIdx.x;
  const int lane = tid & 63;
  const int wid  = tid >> 6;
  const int wr = wid >> 1, wc = wid & 1;
  const int g = lane >> 4, c = lane & 15;
  const long row0 = (long)blockIdx.y * 128;
  const long col0 = (long)blockIdx.x * 128;

  // staging: wave w covers 32 rows (2 insts x 16 rows); lane -> row base+l/4,
  // 16B chunk (l&3)*16 within the 64B row.
  const short* gA = A + (row0 + wid * 32 + (lane >> 2)) * (long)K + (lane & 3) * 8;
  const short* gB = B + (col0 + wid * 32 + (lane >> 2)) * (long)K + (lane & 3) * 8;
  short* lA = As + wid * 1024;   // bytes: wid*2048 (wave-uniform)
  short* lB = Bs + wid * 1024;

  f32x4 acc[4][4];
  const f32x4 z = {0.f, 0.f, 0.f, 0.f};
#pragma unroll
  for (int i = 0; i < 4; i++)
#pragma unroll
    for (int j = 0; j < 4; j++) acc[i][j] = z;

  for (int kt = 0; kt < K; kt += 32) {
    __syncthreads();                       // prev iter reads done
    gload_lds16(gA + kt,            lA);
    gload_lds16(gA + kt + 16 * (long)K, lA + 512);
    gload_lds16(gB + kt,            lB);
    gload_lds16(gB + kt + 16 * (long)K, lB + 512);
    __syncthreads();                       // vmcnt(0) drained by barrier

    bf16x8 af[4], bfr[4];
#pragma unroll
    for (int mf = 0; mf < 4; mf++)
      af[mf] = *reinterpret_cast<const bf16x8*>(As + (wr * 64 + mf * 16 + c) * 32 + g * 8);
#pragma unroll
    for (int nf = 0; nf < 4; nf++)
      bfr[nf] = *reinterpret_cast<const bf16x8*>(Bs + (wc * 64 + nf * 16 + c) * 32 + g * 8);
#pragma unroll
    for (int mf = 0; mf < 4; mf++)
#pragma unroll
      for (int nf = 0; nf < 4; nf++)
        acc[mf][nf] = __builtin_amdgcn_mfma_f32_16x16x32_bf16(af[mf], bfr[nf], acc[mf][nf], 0, 0, 0);
  }

  // epilogue: C/D layout col=lane&15, row=(lane>>4)*4+reg  [m89-verified]
#pragma unroll
  for (int mf = 0; mf < 4; mf++)
#pragma unroll
    for (int nf = 0; nf < 4; nf++)
#pragma unroll
      for (int r = 0; r < 4; r++) {
        const long m = row0 + wr * 64 + mf * 16 + g * 4 + r;
        const long n = col0 + wc * 64 + nf * 16 + c;
        if (Cb) Cb[m * N + n] = (short)f2bf(acc[mf][nf][r]);
        else    Cf[m * N + n] = acc[mf][nf][r] + bias[n];
      }
}

__global__ __launch_bounds__(256) void gemm_qkv_k() {
  gemm_body(g_xb, g_wqkv, g_qkv, nullptr, nullptr, 3 * DMODEL, DMODEL);
}
__global__ __launch_bounds__(256) void gemm_out_k(float* __restrict__ out,
                                                  const float* __restrict__ bias) {
  gemm_body(g_attno, g_wout, nullptr, out, bias, DMODEL, DMODEL);
}

// ---------------- causal flash attention ----------------
// grid = (S/64 q-tiles, B*H). 4 waves/block, wave = 16 q rows. KV tile = 64.
// Q,K fragments straight from global (K-contiguous); V transposed into
// swizzled LDS; P (C-layout) -> swizzled per-wave LDS -> A-layout frags.
__global__ __launch_bounds__(256) void flash_attn() {
  __shared__ short Vt[64 * 64];        // [d][key^((d&7)<<3)]
  __shared__ short Pl[4][16 * 64];     // per wave: [qrow][key^((qrow&7)<<3)]
  const int tid = threadIdx.x;
  const int lane = tid & 63, wid = tid >> 6;
  const int g = lane >> 4, c = lane & 15;
  const int qt = blockIdx.x;
  const int b = blockIdx.y >> 4, h = blockIdx.y & 15;
  const short* base = g_qkv + (size_t)b * SEQ * QKVLD + h * DHEAD;
  const int q0 = qt * 64;
  const int qw = q0 + wid * 16;        // wave's first q row

  // Q fragments: A-layout row=c, k=cc*32+g*8+j
  bf16x8 qf[2];
#pragma unroll
  for (int cc = 0; cc < 2; cc++)
    qf[cc] = *reinterpret_cast<const bf16x8*>(base + (size_t)(qw + c) * QKVLD + cc * 32 + g * 8);

  const f32x4 z = {0.f, 0.f, 0.f, 0.f};
  f32x4 oacc[4];
#pragma unroll
  for (int df = 0; df < 4; df++) oacc[df] = z;
  float mrow[4] = {-__builtin_inff(), -__builtin_inff(), -__builtin_inff(), -__builtin_inff()};
  float lrow[4] = {0.f, 0.f, 0.f, 0.f};

  const int vk = tid & 63;             // V staging: key row
  const int vd0 = (tid >> 6) * 16;     // 16 d-elems per thread

  const int ntile = qt + 1;            // causal: tiles 0..qt
  for (int t = 0; t < ntile; t++) {
    const int k0 = t * 64;
    __syncthreads();                   // everyone done reading Vt of prev tile

    // stage V transposed (issue early; latency hides under QK^T+softmax)
    {
      const short* vrow = base + 2048 + (size_t)(k0 + vk) * QKVLD + vd0;
      bf16x8 v0 = *reinterpret_cast<const bf16x8*>(vrow);
      bf16x8 v1 = *reinterpret_cast<const bf16x8*>(vrow + 8);
#pragma unroll
      for (int j = 0; j < 8; j++) {
        Vt[(vd0 + j) * 64 + (vk ^ ((j & 7) << 3))] = v0[j];
        Vt[(vd0 + 8 + j) * 64 + (vk ^ ((j & 7) << 3))] = v1[j];
      }
    }

    // QK^T: D[q][key], B-frag of K read straight from global
    f32x4 sc[4];
#pragma unroll
    for (int nf = 0; nf < 4; nf++) {
      const short* krow = base + 1024 + (size_t)(k0 + nf * 16 + c) * QKVLD + g * 8;
      bf16x8 kf0 = *reinterpret_cast<const bf16x8*>(krow);
      bf16x8 kf1 = *reinterpret_cast<const bf16x8*>(krow + 32);
      f32x4 s = __builtin_amdgcn_mfma_f32_16x16x32_bf16(qf[0], kf0, z, 0, 0, 0);
      s = __builtin_amdgcn_mfma_f32_16x16x32_bf16(qf[1], kf1, s, 0, 0, 0);
      sc[nf] = s * 0.125f;             // 1/sqrt(64)
    }
    if (t == qt) {                     // diagonal tile: causal mask
#pragma unroll
      for (int nf = 0; nf < 4; nf++)
#pragma unroll
        for (int r = 0; r < 4; r++)
          if (nf * 16 + c > wid * 16 + g * 4 + r) sc[nf][r] = -__builtin_inff();
    }

    // online softmax (rows live in 16-lane groups; reduce via shfl width 16)
    float al[4], rs[4];
#pragma unroll
    for (int r = 0; r < 4; r++) {
      float tm = fmaxf(fmaxf(sc[0][r], sc[1][r]), fmaxf(sc[2][r], sc[3][r]));
      tm = fmaxf(tm, __shfl_xor(tm, 1, 16));
      tm = fmaxf(tm, __shfl_xor(tm, 2, 16));
      tm = fmaxf(tm, __shfl_xor(tm, 4, 16));
      tm = fmaxf(tm, __shfl_xor(tm, 8, 16));
      const float mn = fmaxf(mrow[r], tm);    // finite: diag always unmasked
      al[r] = __expf(mrow[r] - mn);           // first tile: exp(-inf)=0
      mrow[r] = mn;
      rs[r] = 0.f;
    }
#pragma unroll
    for (int nf = 0; nf < 4; nf++)
#pragma unroll
      for (int r = 0; r < 4; r++) {
        const float p = __expf(sc[nf][r] - mrow[r]);
        rs[r] += p;
        const int prow = g * 4 + r;
        Pl[wid][prow * 64 + ((nf * 16 + c) ^ ((prow & 7) << 3))] = (short)f2bf(p);
      }
#pragma unroll
    for (int r = 0; r < 4; r++) {
      float s4 = rs[r];
      s4 += __shfl_xor(s4, 1, 16);
      s4 += __shfl_xor(s4, 2, 16);
      s4 += __shfl_xor(s4, 4, 16);
      s4 += __shfl_xor(s4, 8, 16);
      lrow[r] = lrow[r] * al[r] + s4;
    }
#pragma unroll
    for (int df = 0; df < 4; df++)
#pragma unroll
      for (int r = 0; r < 4; r++) oacc[df][r] *= al[r];

    __syncthreads();                   // Vt writes visible

    // PV: A = P (row=c=qrow, k=key), B = V^T (col=c=d, k=key)
    bf16x8 pa[2];
#pragma unroll
    for (int kc = 0; kc < 2; kc++)
      pa[kc] = *reinterpret_cast<const bf16x8*>(
          &Pl[wid][c * 64 + ((kc * 32 + g * 8) ^ ((c & 7) << 3))]);
#pragma unroll
    for (int df = 0; df < 4; df++)
#pragma unroll
      for (int kc = 0; kc < 2; kc++) {
        const bf16x8 vf = *reinterpret_cast<const bf16x8*>(
            &Vt[(df * 16 + c) * 64 + ((kc * 32 + g * 8) ^ ((c & 7) << 3))]);
        oacc[df] = __builtin_amdgcn_mfma_f32_16x16x32_bf16(pa[kc], vf, oacc[df], 0, 0, 0);
      }
  }

  // epilogue: out[b, qrow, h*64 + d] bf16
#pragma unroll
  for (int r = 0; r < 4; r++) {
    const float inv = 1.0f / lrow[r];
    const size_t orow = ((size_t)b * SEQ + qw + g * 4 + r) * DMODEL + h * DHEAD;
#pragma unroll
    for (int df = 0; df < 4; df++)
      attnoStore: ;
  }
#pragma unroll
  for (int r = 0; r < 4; r++) {
    const float inv = 1.0f / lrow[r];
    const size_t orow = ((size_t)b * SEQ + qw + g * 4 + r) * DMODEL + h * DHEAD;
#pragma unroll
    for (int df = 0; df < 4; df++)
      g_attno[orow + df * 16 + c] = (short)f2bf(oacc[df][r] * inv);
  }
}

extern "C" void kernel_launch(void* const* d_in, const int* in_sizes, int n_in,
                              void* d_out, int out_size, void* d_ws, size_t ws_size,
                              hipStream_t stream) {
  (void)in_sizes; (void)n_in; (void)d_ws; (void)ws_size; (void)out_size;
  const float* x    = (const float*)d_in[0];
  const float* Wqkv = (const float*)d_in[1];
  const float* Wout = (const float*)d_in[2];
  const float* bout = (const float*)d_in[3];
  float* out = (float*)d_out;

  cvt3<<<2048, 256, 0, stream>>>(x, Wqkv, Wout);
  gemm_qkv_k<<<dim3(3 * DMODEL / 128, MROWS / 128), 256, 0, stream>>>();
  flash_attn<<<dim3(SEQ / 64, BATCH * NHEAD), 256, 0, stream>>>();
  gemm_out_k<<<dim3(DMODEL / 128, MROWS / 128), 256, 0, stream>>>(out, bout);
}

// Round 2
// 224.575 us; speedup vs baseline: 1.4083x; 1.4083x over previous
//
// MultiHeadSelfAttention (B=2,S=2048,d=1024,H=16,Dh=64, causal) on MI355X.
// fp32->bf16 cvt -> QKV GEMM (bf16 MFMA) -> causal flash attention (swapped
// QK^T, LDS-staged K/V double-buffered, 1 barrier/tile) -> out GEMM + bias.

#include <hip/hip_runtime.h>
#include <stdint.h>

typedef __attribute__((ext_vector_type(8))) short bf16x8;   // 8 bf16 (4 VGPR)
typedef __attribute__((ext_vector_type(4))) float f32x4;    // MFMA C/D frag
typedef __attribute__((ext_vector_type(4))) unsigned short u16x4;

#define AS1 __attribute__((address_space(1)))
#define AS3 __attribute__((address_space(3)))

#define BATCH 2
#define SEQ   2048
#define DMODEL 1024
#define NHEAD 16
#define DHEAD 64
#define QKVLD 3072           // row stride of qkv buffer
#define MROWS (BATCH*SEQ)    // 4096

__device__ short g_xb   [MROWS * DMODEL];
__device__ short g_wqkv [3*DMODEL * DMODEL];
__device__ short g_wout [DMODEL * DMODEL];
__device__ short g_qkv  [(size_t)MROWS * QKVLD];
__device__ short g_attno[MROWS * DMODEL];

__device__ __forceinline__ unsigned short f2bf(float f) {
  union { float f; unsigned u; } v; v.f = f;
  unsigned r = v.u + 0x7FFFu + ((v.u >> 16) & 1u);
  return (unsigned short)(r >> 16);
}
__device__ __forceinline__ float bf2f(short s) {
  union { unsigned u; float f; } v; v.u = ((unsigned)(unsigned short)s) << 16;
  return v.f;
}
__device__ __forceinline__ void gload_lds16(const void* g, void* l) {
  __builtin_amdgcn_global_load_lds((const AS1 void*)(uintptr_t)g,
                                   (AS3 void*)(uint32_t)(uintptr_t)l, 16, 0, 0);
}

// ---------------- fp32 -> bf16 conversion ----------------
__global__ void cvt3(const float* __restrict__ x, const float* __restrict__ wq,
                     const float* __restrict__ wo) {
  const int N0 = MROWS * DMODEL;
  const int N1 = 3 * DMODEL * DMODEL;
  const int N2 = DMODEL * DMODEL;
  const int total = N0 + N1 + N2;
  int i = (blockIdx.x * blockDim.x + threadIdx.x) * 4;
  const int stride = gridDim.x * blockDim.x * 4;
  for (; i < total; i += stride) {
    const float* src; short* dst; int off;
    if (i < N0)           { src = x;  dst = g_xb;   off = i; }
    else if (i < N0 + N1) { src = wq; dst = g_wqkv; off = i - N0; }
    else                  { src = wo; dst = g_wout; off = i - N0 - N1; }
    float4 v = *reinterpret_cast<const float4*>(src + off);
    u16x4 o = { f2bf(v.x), f2bf(v.y), f2bf(v.z), f2bf(v.w) };
    *reinterpret_cast<u16x4*>(dst + off) = o;
  }
}

// ---------------- GEMM: C[M,N] = A[M,K] * B[N,K]^T (unchanged, m97-style) ---
__device__ __forceinline__ void gemm_body(const short* __restrict__ A,
                                          const short* __restrict__ B,
                                          short* __restrict__ Cb,
                                          float* __restrict__ Cf,
                                          const float* __restrict__ bias,
                                          int N, int K) {
  __shared__ short As[128 * 32];
  __shared__ short Bs[128 * 32];
  const int tid  = threadIdx.x;
  const int lane = tid & 63;
  const int wid  = tid >> 6;
  const int wr = wid >> 1, wc = wid & 1;
  const int g = lane >> 4, c = lane & 15;
  const long row0 = (long)blockIdx.y * 128;
  const long col0 = (long)blockIdx.x * 128;

  const short* gA = A + (row0 + wid * 32 + (lane >> 2)) * (long)K + (lane & 3) * 8;
  const short* gB = B + (col0 + wid * 32 + (lane >> 2)) * (long)K + (lane & 3) * 8;
  short* lA = As + wid * 1024;
  short* lB = Bs + wid * 1024;

  f32x4 acc[4][4];
  const f32x4 z = {0.f, 0.f, 0.f, 0.f};
#pragma unroll
  for (int i = 0; i < 4; i++)
#pragma unroll
    for (int j = 0; j < 4; j++) acc[i][j] = z;

  for (int kt = 0; kt < K; kt += 32) {
    __syncthreads();
    gload_lds16(gA + kt,                lA);
    gload_lds16(gA + kt + 16 * (long)K, lA + 512);
    gload_lds16(gB + kt,                lB);
    gload_lds16(gB + kt + 16 * (long)K, lB + 512);
    __syncthreads();

    bf16x8 af[4], bfr[4];
#pragma unroll
    for (int mf = 0; mf < 4; mf++)
      af[mf] = *reinterpret_cast<const bf16x8*>(As + (wr * 64 + mf * 16 + c) * 32 + g * 8);
#pragma unroll
    for (int nf = 0; nf < 4; nf++)
      bfr[nf] = *reinterpret_cast<const bf16x8*>(Bs + (wc * 64 + nf * 16 + c) * 32 + g * 8);
#pragma unroll
    for (int mf = 0; mf < 4; mf++)
#pragma unroll
      for (int nf = 0; nf < 4; nf++)
        acc[mf][nf] = __builtin_amdgcn_mfma_f32_16x16x32_bf16(af[mf], bfr[nf], acc[mf][nf], 0, 0, 0);
  }

#pragma unroll
  for (int mf = 0; mf < 4; mf++)
#pragma unroll
    for (int nf = 0; nf < 4; nf++)
#pragma unroll
      for (int r = 0; r < 4; r++) {
        const long m = row0 + wr * 64 + mf * 16 + g * 4 + r;
        const long n = col0 + wc * 64 + nf * 16 + c;
        if (Cb) Cb[m * N + n] = (short)f2bf(acc[mf][nf][r]);
        else    Cf[m * N + n] = acc[mf][nf][r] + bias[n];
      }
}

__global__ __launch_bounds__(256) void gemm_qkv_k() {
  gemm_body(g_xb, g_wqkv, g_qkv, nullptr, nullptr, 3 * DMODEL, DMODEL);
}
__global__ __launch_bounds__(256) void gemm_out_k(float* __restrict__ out,
                                                  const float* __restrict__ bias) {
  gemm_body(g_attno, g_wout, nullptr, out, bias, DMODEL, DMODEL);
}

// ---------------- causal flash attention v2 ----------------
// grid = (B*H=32, S/128=16), 4 waves/block, wave owns 32 q rows. KV tile 64.
// Swapped QK^T: S^T = mfma(A=K, B=Q) -> lane holds 16 keys of q-row (lane&15)
// per n-frag -> softmax reduce = in-lane tree + 2 shfls.
// K: global_load_lds, linear LDS + pre-swizzled source, swizzled b128 reads.
// V: reg-loaded early, written transposed+swizzled. Both double-buffered;
// ONE barrier per tile. P per-wave LDS (no barrier, lgkmcnt only).
__global__ __launch_bounds__(256, 2) void flash_attn() {
  __shared__ short Kl[2][64 * 64];
  __shared__ short Vt[2][64 * 64];
  __shared__ short Pl[4][32 * 64];
  const int tid = threadIdx.x;
  const int lane = tid & 63, wid = tid >> 6;
  const int g = (lane >> 4) & 3, c = lane & 15;
  const int b = blockIdx.x >> 4, h = blockIdx.x & 15;
  const int qb = 15 - (int)blockIdx.y;      // long blocks dispatch first
  const short* base = g_qkv + (size_t)b * SEQ * QKVLD + h * DHEAD;
  const int q0 = qb * 128;
  const int qw = q0 + wid * 32;
  const int nt = 2 * qb + 2;

  // Q B-frags (col=c -> q row, k = kc*32+g*8+j), pre-scaled by 1/8 (exact)
  bf16x8 qf[2][2];
#pragma unroll
  for (int n = 0; n < 2; n++)
#pragma unroll
    for (int kc = 0; kc < 2; kc++) {
      bf16x8 raw = *reinterpret_cast<const bf16x8*>(
          base + (size_t)(qw + n * 16 + c) * QKVLD + kc * 32 + g * 8);
#pragma unroll
      for (int j = 0; j < 8; j++) raw[j] = (short)f2bf(bf2f(raw[j]) * 0.125f);
      qf[n][kc] = raw;
    }

  f32x4 oacc[2][4];
  const f32x4 z = {0.f, 0.f, 0.f, 0.f};
#pragma unroll
  for (int mq = 0; mq < 2; mq++)
#pragma unroll
    for (int nd = 0; nd < 4; nd++) oacc[mq][nd] = z;
  float mrow[2] = {-__builtin_inff(), -__builtin_inff()};
  float lrow[2] = {0.f, 0.f};

  // K staging geometry: inst covers 8 rows x 128B; lane -> row l>>3, chunk l&7.
  // LDS linear; SOURCE chunk pre-swizzled: csrc = (l&7) ^ (row&7), row&7 = l>>3.
  const int srow = lane >> 3;
  const int scol = (lane & 7) ^ srow;
  const short* kgsrc = base + 1024 + (size_t)(wid * 16 + srow) * QKVLD + scol * 8;
  // V: lane loads row (k0+lane), d-chunk wid*16 (2x bf16x8)
  const short* vgsrc = base + 2048 + (size_t)lane * QKVLD + wid * 16;

  // prologue: stage tile 0
  gload_lds16(kgsrc,                      &Kl[0][wid * 1024]);
  gload_lds16(kgsrc + (size_t)8 * QKVLD,  &Kl[0][wid * 1024 + 512]);
  {
    bf16x8 v0 = *reinterpret_cast<const bf16x8*>(vgsrc);
    bf16x8 v1 = *reinterpret_cast<const bf16x8*>(vgsrc + 8);
#pragma unroll
    for (int j = 0; j < 8; j++) {
      Vt[0][(wid * 16 + j) * 64 + (lane ^ (j << 3))] = v0[j];
      Vt[0][(wid * 16 + 8 + j) * 64 + (lane ^ (j << 3))] = v1[j];
    }
  }
  __syncthreads();

  for (int t = 0; t < nt; t++) {
    const int cur = t & 1;
    const int k0 = t * 64;
    const bool stage = (t + 1 < nt);
    bf16x8 vr0, vr1;
    if (stage) {   // issue next tile's loads first (latency hides under compute)
      const size_t roff = (size_t)(k0 + 64) * QKVLD;
      gload_lds16(kgsrc + roff,                     &Kl[cur ^ 1][wid * 1024]);
      gload_lds16(kgsrc + roff + (size_t)8 * QKVLD, &Kl[cur ^ 1][wid * 1024 + 512]);
      vr0 = *reinterpret_cast<const bf16x8*>(vgsrc + roff);
      vr1 = *reinterpret_cast<const bf16x8*>(vgsrc + roff + 8);
    }
    if (k0 <= qw + 31) {                 // wave-uniform: skip fully-masked tiles
      // ---- QK^T (swapped): sc[m][n], D[key=m*16+g*4+r][q=n*16+c] ----
      f32x4 sc[4][2];
#pragma unroll
      for (int m = 0; m < 4; m++) {
        const short* kr = &Kl[cur][(m * 16 + c) * 64];
        bf16x8 ka0 = *reinterpret_cast<const bf16x8*>(kr + ((g ^ (c & 7)) << 3));
        bf16x8 ka1 = *reinterpret_cast<const bf16x8*>(kr + (((4 + g) ^ (c & 7)) << 3));
#pragma unroll
        for (int n = 0; n < 2; n++) {
          f32x4 s = __builtin_amdgcn_mfma_f32_16x16x32_bf16(ka0, qf[n][0], z, 0, 0, 0);
          s = __builtin_amdgcn_mfma_f32_16x16x32_bf16(ka1, qf[n][1], s, 0, 0, 0);
          sc[m][n] = s;
        }
      }
      if (k0 + 63 > qw) {                // diagonal overlap: causal mask
#pragma unroll
        for (int m = 0; m < 4; m++)
#pragma unroll
          for (int n = 0; n < 2; n++)
#pragma unroll
            for (int r = 0; r < 4; r++)
              if (k0 + m * 16 + g * 4 + r > qw + n * 16 + c)
                sc[m][n][r] = -__builtin_inff();
      }
      // ---- online softmax (q-row = n*16+c per lane) ----
      float aln[2];
#pragma unroll
      for (int n = 0; n < 2; n++) {
        f32x4 mm0 = sc[0][n], mm1 = sc[1][n];
#pragma unroll
        for (int r = 0; r < 4; r++) {
          mm0[r] = fmaxf(mm0[r], sc[2][n][r]);
          mm1[r] = fmaxf(mm1[r], sc[3][n][r]);
        }
        float tm = fmaxf(fmaxf(fmaxf(mm0[0], mm0[1]), fmaxf(mm0[2], mm0[3])),
                         fmaxf(fmaxf(mm1[0], mm1[1]), fmaxf(mm1[2], mm1[3])));
        tm = fmaxf(tm, __shfl_xor(tm, 16, 64));
        tm = fmaxf(tm, __shfl_xor(tm, 32, 64));
        const float mn = fmaxf(mrow[n], tm);
        aln[n] = __expf(mrow[n] - mn);
        mrow[n] = mn;
        float rs = 0.f;
        const int q = n * 16 + c;
#pragma unroll
        for (int m = 0; m < 4; m++) {
          u16x4 pb;
#pragma unroll
          for (int r = 0; r < 4; r++) {
            const float p = __expf(sc[m][n][r] - mn);
            rs += p;
            pb[r] = f2bf(p);
          }
          const int idx = q * 64 + ((m * 16 + g * 4) ^ ((c & 7) << 3));
          *reinterpret_cast<u16x4*>(&Pl[wid][idx]) = pb;
        }
        rs += __shfl_xor(rs, 16, 64);
        rs += __shfl_xor(rs, 32, 64);
        lrow[n] = lrow[n] * aln[n] + rs;
      }
      // rescale O (O rows live at g*4+r; al lives at lane q&15 -> shfl)
#pragma unroll
      for (int mq = 0; mq < 2; mq++)
#pragma unroll
        for (int r = 0; r < 4; r++) {
          const float alr = __shfl(aln[mq], g * 4 + r, 64);
#pragma unroll
          for (int nd = 0; nd < 4; nd++) oacc[mq][nd][r] *= alr;
        }
      asm volatile("s_waitcnt lgkmcnt(0)" ::: "memory");  // P writes visible in-wave
      // ---- PV: A=P[q][key], B=V^T[d][key] ----
      bf16x8 pa[2][2];
#pragma unroll
      for (int mq = 0; mq < 2; mq++) {
        const int q = mq * 16 + c;
#pragma unroll
        for (int kc = 0; kc < 2; kc++)
          pa[mq][kc] = *reinterpret_cast<const bf16x8*>(
              &Pl[wid][q * 64 + ((kc * 32 + g * 8) ^ ((c & 7) << 3))]);
      }
#pragma unroll
      for (int nd = 0; nd < 4; nd++) {
        const int d = nd * 16 + c;
#pragma unroll
        for (int kc = 0; kc < 2; kc++) {
          const bf16x8 vf = *reinterpret_cast<const bf16x8*>(
              &Vt[cur][d * 64 + ((kc * 32 + g * 8) ^ ((c & 7) << 3))]);
#pragma unroll
          for (int mq = 0; mq < 2; mq++)
            oacc[mq][nd] = __builtin_amdgcn_mfma_f32_16x16x32_bf16(pa[mq][kc], vf, oacc[mq][nd], 0, 0, 0);
        }
      }
    }
    if (stage) {   // write next V tile (vmcnt dep handled by compiler)
#pragma unroll
      for (int j = 0; j < 8; j++) {
        Vt[cur ^ 1][(wid * 16 + j) * 64 + (lane ^ (j << 3))] = vr0[j];
        Vt[cur ^ 1][(wid * 16 + 8 + j) * 64 + (lane ^ (j << 3))] = vr1[j];
      }
    }
    __syncthreads();   // Kl[cur^1] (gload) + Vt[cur^1] ready for t+1
  }

  // epilogue: O[q][d] -> g_attno (scale by 1/l via shfl from lane q&15)
  const float inv0 = 1.f / lrow[0], inv1 = 1.f / lrow[1];
#pragma unroll
  for (int mq = 0; mq < 2; mq++) {
    const float invm = mq ? inv1 : inv0;
#pragma unroll
    for (int r = 0; r < 4; r++) {
      const float linv = __shfl(invm, g * 4 + r, 64);
      const size_t orow = ((size_t)b * SEQ + qw + mq * 16 + g * 4 + r) * DMODEL + h * DHEAD;
#pragma unroll
      for (int nd = 0; nd < 4; nd++)
        g_attno[orow + nd * 16 + c] = (short)f2bf(oacc[mq][nd][r] * linv);
    }
  }
}

extern "C" void kernel_launch(void* const* d_in, const int* in_sizes, int n_in,
                              void* d_out, int out_size, void* d_ws, size_t ws_size,
                              hipStream_t stream) {
  (void)in_sizes; (void)n_in; (void)d_ws; (void)ws_size; (void)out_size;
  const float* x    = (const float*)d_in[0];
  const float* Wqkv = (const float*)d_in[1];
  const float* Wout = (const float*)d_in[2];
  const float* bout = (const float*)d_in[3];
  float* out = (float*)d_out;

  cvt3<<<2048, 256, 0, stream>>>(x, Wqkv, Wout);
  gemm_qkv_k<<<dim3(3 * DMODEL / 128, MROWS / 128), 256, 0, stream>>>();
  flash_attn<<<dim3(BATCH * NHEAD, SEQ / 128), 256, 0, stream>>>();
  gemm_out_k<<<dim3(DMODEL / 128, MROWS / 128), 256, 0, stream>>>(out, bout);
}

// Round 6
// 217.739 us; speedup vs baseline: 1.4525x; 1.0314x over previous
//
// MultiHeadSelfAttention (B=2,S=2048,d=1024,H=16,Dh=64, causal) on MI355X.
// fp32->bf16 cvt -> QKV GEMM (bf16 MFMA) -> causal flash attention (swapped
// QK^T, triple-buffered K/V, counted-vmcnt raw-barrier pipeline, exp2 softmax,
// defer-max, setprio) -> out GEMM + bias. XCD-chunked GEMM grids.
// [Round 5: resubmission — rounds 2/3/4 never ran (GPU acquisition timeouts).]

#include <hip/hip_runtime.h>
#include <stdint.h>

typedef __attribute__((ext_vector_type(8))) short bf16x8;   // 8 bf16 (4 VGPR)
typedef __attribute__((ext_vector_type(4))) float f32x4;    // MFMA C/D frag
typedef __attribute__((ext_vector_type(4))) unsigned short u16x4;

#define AS1 __attribute__((address_space(1)))
#define AS3 __attribute__((address_space(3)))

#define BATCH 2
#define SEQ   2048
#define DMODEL 1024
#define NHEAD 16
#define DHEAD 64
#define QKVLD 3072           // row stride of qkv buffer
#define MROWS (BATCH*SEQ)    // 4096

__device__ short g_xb   [MROWS * DMODEL];
__device__ short g_wqkv [3*DMODEL * DMODEL];
__device__ short g_wout [DMODEL * DMODEL];
__device__ short g_qkv  [(size_t)MROWS * QKVLD];
__device__ short g_attno[MROWS * DMODEL];

__device__ __forceinline__ unsigned short f2bf(float f) {
  union { float f; unsigned u; } v; v.f = f;
  unsigned r = v.u + 0x7FFFu + ((v.u >> 16) & 1u);
  return (unsigned short)(r >> 16);
}
__device__ __forceinline__ float bf2f(short s) {
  union { unsigned u; float f; } v; v.u = ((unsigned)(unsigned short)s) << 16;
  return v.f;
}
__device__ __forceinline__ void gload_lds16(const void* g, void* l) {
  __builtin_amdgcn_global_load_lds((const AS1 void*)(uintptr_t)g,
                                   (AS3 void*)(uint32_t)(uintptr_t)l, 16, 0, 0);
}

// ---------------- fp32 -> bf16 conversion ----------------
__global__ void cvt3(const float* __restrict__ x, const float* __restrict__ wq,
                     const float* __restrict__ wo) {
  const int N0 = MROWS * DMODEL;
  const int N1 = 3 * DMODEL * DMODEL;
  const int N2 = DMODEL * DMODEL;
  const int total = N0 + N1 + N2;
  int i = (blockIdx.x * blockDim.x + threadIdx.x) * 4;
  const int stride = gridDim.x * blockDim.x * 4;
  for (; i < total; i += stride) {
    const float* src; short* dst; int off;
    if (i < N0)           { src = x;  dst = g_xb;   off = i; }
    else if (i < N0 + N1) { src = wq; dst = g_wqkv; off = i - N0; }
    else                  { src = wo; dst = g_wout; off = i - N0 - N1; }
    float4 v = *reinterpret_cast<const float4*>(src + off);
    u16x4 o = { f2bf(v.x), f2bf(v.y), f2bf(v.z), f2bf(v.w) };
    *reinterpret_cast<u16x4*>(dst + off) = o;
  }
}

// ---------------- GEMM: C[M,N] = A[M,K] * B[N,K]^T (m97-style body) --------
__device__ __forceinline__ void gemm_body(const short* __restrict__ A,
                                          const short* __restrict__ B,
                                          short* __restrict__ Cb,
                                          float* __restrict__ Cf,
                                          const float* __restrict__ bias,
                                          int N, int K, int bx, int by) {
  __shared__ short As[128 * 32];
  __shared__ short Bs[128 * 32];
  const int tid  = threadIdx.x;
  const int lane = tid & 63;
  const int wid  = tid >> 6;
  const int wr = wid >> 1, wc = wid & 1;
  const int g = lane >> 4, c = lane & 15;
  const long row0 = (long)by * 128;
  const long col0 = (long)bx * 128;

  const short* gA = A + (row0 + wid * 32 + (lane >> 2)) * (long)K + (lane & 3) * 8;
  const short* gB = B + (col0 + wid * 32 + (lane >> 2)) * (long)K + (lane & 3) * 8;
  short* lA = As + wid * 1024;
  short* lB = Bs + wid * 1024;

  f32x4 acc[4][4];
  const f32x4 z = {0.f, 0.f, 0.f, 0.f};
#pragma unroll
  for (int i = 0; i < 4; i++)
#pragma unroll
    for (int j = 0; j < 4; j++) acc[i][j] = z;

  for (int kt = 0; kt < K; kt += 32) {
    __syncthreads();
    gload_lds16(gA + kt,                lA);
    gload_lds16(gA + kt + 16 * (long)K, lA + 512);
    gload_lds16(gB + kt,                lB);
    gload_lds16(gB + kt + 16 * (long)K, lB + 512);
    __syncthreads();

    bf16x8 af[4], bfr[4];
#pragma unroll
    for (int mf = 0; mf < 4; mf++)
      af[mf] = *reinterpret_cast<const bf16x8*>(As + (wr * 64 + mf * 16 + c) * 32 + g * 8);
#pragma unroll
    for (int nf = 0; nf < 4; nf++)
      bfr[nf] = *reinterpret_cast<const bf16x8*>(Bs + (wc * 64 + nf * 16 + c) * 32 + g * 8);
#pragma unroll
    for (int mf = 0; mf < 4; mf++)
#pragma unroll
      for (int nf = 0; nf < 4; nf++)
        acc[mf][nf] = __builtin_amdgcn_mfma_f32_16x16x32_bf16(af[mf], bfr[nf], acc[mf][nf], 0, 0, 0);
  }

#pragma unroll
  for (int mf = 0; mf < 4; mf++)
#pragma unroll
    for (int nf = 0; nf < 4; nf++)
#pragma unroll
      for (int r = 0; r < 4; r++) {
        const long m = row0 + wr * 64 + mf * 16 + g * 4 + r;
        const long n = col0 + wc * 64 + nf * 16 + c;
        if (Cb) Cb[m * N + n] = (short)f2bf(acc[mf][nf][r]);
        else    Cf[m * N + n] = acc[mf][nf][r] + bias[n];
      }
}

// XCD-chunked grids: id%8 = XCD (round-robin assumption; perf-only). Each XCD
// gets 4 M-rows x all N-cols, by-fastest within -> A-panels (1MB) + current
// B-panel L2-resident, B streamed once per XCD.
__global__ __launch_bounds__(256) void gemm_qkv_k() {   // grid 768 (24x32)
  const int id = blockIdx.x;
  const int j = id >> 3;                       // 0..95
  const int bx = j >> 2;                       // 0..23 (N)
  const int by = ((id & 7) << 2) | (j & 3);    // 0..31 (M)
  gemm_body(g_xb, g_wqkv, g_qkv, nullptr, nullptr, 3 * DMODEL, DMODEL, bx, by);
}
__global__ __launch_bounds__(256) void gemm_out_k(float* __restrict__ out,
                                                  const float* __restrict__ bias) { // grid 256 (8x32)
  const int id = blockIdx.x;
  const int j = id >> 3;                       // 0..31
  const int bx = j >> 2;                       // 0..7 (N)
  const int by = ((id & 7) << 2) | (j & 3);    // 0..31 (M)
  gemm_body(g_attno, g_wout, nullptr, out, bias, DMODEL, DMODEL, bx, by);
}

// ---------------- causal flash attention v3 ----------------
// 512 blocks (2/CU), 4 waves, wave = 32 q rows, KV tile 64, triple-buffered
// K/V LDS, stage t+2 at tile t, raw s_barrier (no vmcnt drain), exp2 softmax
// with defer-max, setprio around MFMA clusters.
__global__ __launch_bounds__(256, 2) void flash_attn() {
  __shared__ short Kl[3][64 * 64];     // 24 KB
  __shared__ short Vt[3][64 * 64];     // 24 KB
  __shared__ short Pl[4][32 * 64];     // 16 KB
  const int tid = threadIdx.x;
  const int lane = tid & 63, wid = tid >> 6;
  const int g = (lane >> 4) & 3, c = lane & 15;
  const int id = blockIdx.x;
  const int bh = id & 31;              // all q-blocks of a head share id%8 -> same XCD
  const int b = bh >> 4, h = bh & 15;
  const int qb = (id < 256) ? (15 - (id >> 5)) : ((id - 256) >> 5);  // pair sums = 15
  const short* base = g_qkv + (size_t)b * SEQ * QKVLD + h * DHEAD;
  const int qw = qb * 128 + wid * 32;
  const int nt = 2 * qb + 2;

  // Q B-frags, pre-scaled by (1/sqrt(64)) * log2(e)  -> exp2-domain scores
  const float QS = 0.18033688011112042f;
  bf16x8 qf[2][2];
#pragma unroll
  for (int n = 0; n < 2; n++)
#pragma unroll
    for (int kc = 0; kc < 2; kc++) {
      bf16x8 raw = *reinterpret_cast<const bf16x8*>(
          base + (size_t)(qw + n * 16 + c) * QKVLD + kc * 32 + g * 8);
#pragma unroll
      for (int j = 0; j < 8; j++) raw[j] = (short)f2bf(bf2f(raw[j]) * QS);
      qf[n][kc] = raw;
    }

  f32x4 oacc[2][4];
  const f32x4 z = {0.f, 0.f, 0.f, 0.f};
#pragma unroll
  for (int mq = 0; mq < 2; mq++)
#pragma unroll
    for (int nd = 0; nd < 4; nd++) oacc[mq][nd] = z;
  float mrow[2] = {-__builtin_inff(), -__builtin_inff()};
  float lrow[2] = {0.f, 0.f};

  // K staging: 2 gload insts/wave, 8 rows x 128B each; source chunk
  // pre-swizzled (csrc = (l&7)^(l>>3)) so swizzled b128 reads are ~2-way.
  const int srow = lane >> 3;
  const int scol = (lane & 7) ^ srow;
  const short* kgsrc = base + 1024 + (size_t)(wid * 16 + srow) * QKVLD + scol * 8;
  // V: lane loads kv-row (k0+lane), d-chunk wid*16 (2x bf16x8), reg-staged.
  const short* vgsrc = base + 2048 + (size_t)lane * QKVLD + wid * 16;

  // ---- prologue: stage tiles 0 and 1 (nt >= 2 always) ----
  {
    bf16x8 a0 = *reinterpret_cast<const bf16x8*>(vgsrc);
    bf16x8 a1 = *reinterpret_cast<const bf16x8*>(vgsrc + 8);
    gload_lds16(kgsrc,                     &Kl[0][wid * 1024]);
    gload_lds16(kgsrc + (size_t)8 * QKVLD, &Kl[0][wid * 1024 + 512]);
    const size_t r1 = (size_t)64 * QKVLD;
    bf16x8 b0 = *reinterpret_cast<const bf16x8*>(vgsrc + r1);
    bf16x8 b1 = *reinterpret_cast<const bf16x8*>(vgsrc + r1 + 8);
    gload_lds16(kgsrc + r1,                     &Kl[1][wid * 1024]);
    gload_lds16(kgsrc + r1 + (size_t)8 * QKVLD, &Kl[1][wid * 1024 + 512]);
#pragma unroll
    for (int j = 0; j < 8; j++) {       // compiler auto-waits a0/a1 (vmcnt<=6)
      Vt[0][(wid * 16 + j) * 64 + (lane ^ (j << 3))] = a0[j];
      Vt[0][(wid * 16 + 8 + j) * 64 + (lane ^ (j << 3))] = a1[j];
    }
#pragma unroll
    for (int j = 0; j < 8; j++) {       // auto-wait b0/b1 (vmcnt<=2) retires K0
      Vt[1][(wid * 16 + j) * 64 + (lane ^ (j << 3))] = b0[j];
      Vt[1][(wid * 16 + 8 + j) * 64 + (lane ^ (j << 3))] = b1[j];
    }
    asm volatile("s_waitcnt lgkmcnt(0)" ::: "memory");
    __builtin_amdgcn_sched_barrier(0);
    __builtin_amdgcn_s_barrier();
    asm volatile("" ::: "memory");
  }

  int cur = 0;
  for (int t = 0; t < nt; t++) {
    const int sidx = (cur + 2 >= 3) ? cur - 1 : cur + 2;   // (t+2)%3
    const bool sl = (t + 2 < nt);
    bf16x8 vr0, vr1;
    if (sl) {                            // issue tile t+2 loads at tile-t top
      const size_t roff = (size_t)(t + 2) * 64 * QKVLD;
      vr0 = *reinterpret_cast<const bf16x8*>(vgsrc + roff);
      vr1 = *reinterpret_cast<const bf16x8*>(vgsrc + roff + 8);
      gload_lds16(kgsrc + roff,                     &Kl[sidx][wid * 1024]);
      gload_lds16(kgsrc + roff + (size_t)8 * QKVLD, &Kl[sidx][wid * 1024 + 512]);
    }
    const int k0 = t * 64;
    if (k0 <= qw + 31) {                 // wave-uniform compute predicate
      // ---- QK^T (swapped): D[key=m*16+g*4+r][q=n*16+c] ----
      f32x4 sc[4][2];
      __builtin_amdgcn_s_setprio(1);
#pragma unroll
      for (int m = 0; m < 4; m++) {
        const short* kr = &Kl[cur][(m * 16 + c) * 64];
        bf16x8 ka0 = *reinterpret_cast<const bf16x8*>(kr + ((g ^ (c & 7)) << 3));
        bf16x8 ka1 = *reinterpret_cast<const bf16x8*>(kr + (((4 + g) ^ (c & 7)) << 3));
#pragma unroll
        for (int n = 0; n < 2; n++) {
          f32x4 s = __builtin_amdgcn_mfma_f32_16x16x32_bf16(ka0, qf[n][0], z, 0, 0, 0);
          s = __builtin_amdgcn_mfma_f32_16x16x32_bf16(ka1, qf[n][1], s, 0, 0, 0);
          sc[m][n] = s;
        }
      }
      __builtin_amdgcn_s_setprio(0);
      if (k0 + 63 > qw) {                // diagonal overlap: causal mask
#pragma unroll
        for (int m = 0; m < 4; m++)
#pragma unroll
          for (int n = 0; n < 2; n++)
#pragma unroll
            for (int r = 0; r < 4; r++)
              if (k0 + m * 16 + g * 4 + r > qw + n * 16 + c)
                sc[m][n][r] = -__builtin_inff();
      }
      // ---- online softmax, exp2 domain, defer-max THR=8 ----
      float tm[2];
#pragma unroll
      for (int n = 0; n < 2; n++) {
        f32x4 mm0 = sc[0][n], mm1 = sc[1][n];
#pragma unroll
        for (int r = 0; r < 4; r++) {
          mm0[r] = fmaxf(mm0[r], sc[2][n][r]);
          mm1[r] = fmaxf(mm1[r], sc[3][n][r]);
        }
        float v = fmaxf(fmaxf(fmaxf(mm0[0], mm0[1]), fmaxf(mm0[2], mm0[3])),
                        fmaxf(fmaxf(mm1[0], mm1[1]), fmaxf(mm1[2], mm1[3])));
        v = fmaxf(v, __shfl_xor(v, 16, 64));
        v = fmaxf(v, __shfl_xor(v, 32, 64));
        tm[n] = v;
      }
      const bool grow = (tm[0] > mrow[0] + 8.f) || (tm[1] > mrow[1] + 8.f);
      if (__any(grow)) {
        float aln[2];
#pragma unroll
        for (int n = 0; n < 2; n++) {
          const float mn = fmaxf(mrow[n], tm[n]);
          aln[n] = exp2f(mrow[n] - mn);   // first tile: exp2(-inf)=0
          mrow[n] = mn;
          lrow[n] *= aln[n];
        }
#pragma unroll
        for (int mq = 0; mq < 2; mq++)
#pragma unroll
          for (int r = 0; r < 4; r++) {
            const float alr = __shfl(aln[mq], g * 4 + r, 64);
#pragma unroll
            for (int nd = 0; nd < 4; nd++) oacc[mq][nd][r] *= alr;
          }
      }
#pragma unroll
      for (int n = 0; n < 2; n++) {
        float rs = 0.f;
        const int q = n * 16 + c;
#pragma unroll
        for (int m = 0; m < 4; m++) {
          u16x4 pb;
#pragma unroll
          for (int r = 0; r < 4; r++) {
            const float p = exp2f(sc[m][n][r] - mrow[n]);
            rs += p;
            pb[r] = f2bf(p);
          }
          const int idx = q * 64 + ((m * 16 + g * 4) ^ ((c & 7) << 3));
          *reinterpret_cast<u16x4*>(&Pl[wid][idx]) = pb;
        }
        rs += __shfl_xor(rs, 16, 64);
        rs += __shfl_xor(rs, 32, 64);
        lrow[n] += rs;
      }
      asm volatile("s_waitcnt lgkmcnt(0)" ::: "memory");  // P visible in-wave
      // ---- PV: A=P[q][key], B=V^T[d][key] ----
      bf16x8 pa[2][2];
#pragma unroll
      for (int mq = 0; mq < 2; mq++) {
        const int q = mq * 16 + c;
#pragma unroll
        for (int kc = 0; kc < 2; kc++)
          pa[mq][kc] = *reinterpret_cast<const bf16x8*>(
              &Pl[wid][q * 64 + ((kc * 32 + g * 8) ^ ((c & 7) << 3))]);
      }
      __builtin_amdgcn_s_setprio(1);
#pragma unroll
      for (int nd = 0; nd < 4; nd++) {
        const int d = nd * 16 + c;
#pragma unroll
        for (int kc = 0; kc < 2; kc++) {
          const bf16x8 vf = *reinterpret_cast<const bf16x8*>(
              &Vt[cur][d * 64 + ((kc * 32 + g * 8) ^ ((c & 7) << 3))]);
#pragma unroll
          for (int mq = 0; mq < 2; mq++)
            oacc[mq][nd] = __builtin_amdgcn_mfma_f32_16x16x32_bf16(pa[mq][kc], vf, oacc[mq][nd], 0, 0, 0);
        }
      }
      __builtin_amdgcn_s_setprio(0);
    }
    // V write for t+2 (auto vmcnt wait on vr retires K(t+1) gloads in-order)
    if (sl) {
#pragma unroll
      for (int j = 0; j < 8; j++) {
        Vt[sidx][(wid * 16 + j) * 64 + (lane ^ (j << 3))] = vr0[j];
        Vt[sidx][(wid * 16 + 8 + j) * 64 + (lane ^ (j << 3))] = vr1[j];
      }
    } else {
      asm volatile("s_waitcnt vmcnt(0)" ::: "memory");    // drain tail gloads
    }
    asm volatile("s_waitcnt lgkmcnt(0)" ::: "memory");
    __builtin_amdgcn_sched_barrier(0);
    __builtin_amdgcn_s_barrier();
    asm volatile("" ::: "memory");
    cur = (cur + 1 == 3) ? 0 : cur + 1;
  }

  // epilogue
  const float inv0 = 1.f / lrow[0], inv1 = 1.f / lrow[1];
#pragma unroll
  for (int mq = 0; mq < 2; mq++) {
    const float invm = mq ? inv1 : inv0;
#pragma unroll
    for (int r = 0; r < 4; r++) {
      const float linv = __shfl(invm, g * 4 + r, 64);
      const size_t orow = ((size_t)b * SEQ + qw + mq * 16 + g * 4 + r) * DMODEL + h * DHEAD;
#pragma unroll
      for (int nd = 0; nd < 4; nd++)
        g_attno[orow + nd * 16 + c] = (short)f2bf(oacc[mq][nd][r] * linv);
    }
  }
}

extern "C" void kernel_launch(void* const* d_in, const int* in_sizes, int n_in,
                              void* d_out, int out_size, void* d_ws, size_t ws_size,
                              hipStream_t stream) {
  (void)in_sizes; (void)n_in; (void)d_ws; (void)ws_size; (void)out_size;
  const float* x    = (const float*)d_in[0];
  const float* Wqkv = (const float*)d_in[1];
  const float* Wout = (const float*)d_in[2];
  const float* bout = (const float*)d_in[3];
  float* out = (float*)d_out;

  cvt3<<<2048, 256, 0, stream>>>(x, Wqkv, Wout);
  gemm_qkv_k<<<768, 256, 0, stream>>>();
  flash_attn<<<512, 256, 0, stream>>>();
  gemm_out_k<<<256, 256, 0, stream>>>(out, bout);
}

// Round 8
// 212.803 us; speedup vs baseline: 1.4861x; 1.0232x over previous
//
// MultiHeadSelfAttention (B=2,S=2048,d=1024,H=16,Dh=64, causal) on MI355X.
// cvt -> QKV GEMM -> V-transpose -> flash v4 (qblock=64, perfectly pair-balanced
// 33 tiles/block, K & V^T both via global_load_lds triple-buffer, counted
// vmcnt(4) raw-barrier pipeline, swapped QK^T, exp2 softmax, defer-max)
// -> out GEMM + bias. XCD-chunked GEMM grids.
// [Round 7: resubmission — round 6's v4 never ran (GPU acquisition timeout).]

#include <hip/hip_runtime.h>
#include <stdint.h>

typedef __attribute__((ext_vector_type(8))) short bf16x8;   // 8 bf16 (4 VGPR)
typedef __attribute__((ext_vector_type(4))) float f32x4;    // MFMA C/D frag
typedef __attribute__((ext_vector_type(4))) unsigned short u16x4;

#define AS1 __attribute__((address_space(1)))
#define AS3 __attribute__((address_space(3)))

#define BATCH 2
#define SEQ   2048
#define DMODEL 1024
#define NHEAD 16
#define DHEAD 64
#define QKVLD 3072           // row stride of qkv buffer
#define MROWS (BATCH*SEQ)    // 4096

__device__ short g_xb   [MROWS * DMODEL];
__device__ short g_wqkv [3*DMODEL * DMODEL];
__device__ short g_wout [DMODEL * DMODEL];
__device__ short g_qkv  [(size_t)MROWS * QKVLD];
__device__ short g_vt   [(size_t)BATCH*NHEAD * DHEAD * SEQ];  // V^T [bh][d][s] 8MB
__device__ short g_attno[MROWS * DMODEL];

__device__ __forceinline__ unsigned short f2bf(float f) {
  union { float f; unsigned u; } v; v.f = f;
  unsigned r = v.u + 0x7FFFu + ((v.u >> 16) & 1u);
  return (unsigned short)(r >> 16);
}
__device__ __forceinline__ float bf2f(short s) {
  union { unsigned u; float f; } v; v.u = ((unsigned)(unsigned short)s) << 16;
  return v.f;
}
__device__ __forceinline__ void gload_lds16(const void* g, void* l) {
  __builtin_amdgcn_global_load_lds((const AS1 void*)(uintptr_t)g,
                                   (AS3 void*)(uint32_t)(uintptr_t)l, 16, 0, 0);
}

// ---------------- fp32 -> bf16 conversion ----------------
__global__ void cvt3(const float* __restrict__ x, const float* __restrict__ wq,
                     const float* __restrict__ wo) {
  const int N0 = MROWS * DMODEL;
  const int N1 = 3 * DMODEL * DMODEL;
  const int N2 = DMODEL * DMODEL;
  const int total = N0 + N1 + N2;
  int i = (blockIdx.x * blockDim.x + threadIdx.x) * 4;
  const int stride = gridDim.x * blockDim.x * 4;
  for (; i < total; i += stride) {
    const float* src; short* dst; int off;
    if (i < N0)           { src = x;  dst = g_xb;   off = i; }
    else if (i < N0 + N1) { src = wq; dst = g_wqkv; off = i - N0; }
    else                  { src = wo; dst = g_wout; off = i - N0 - N1; }
    float4 v = *reinterpret_cast<const float4*>(src + off);
    u16x4 o = { f2bf(v.x), f2bf(v.y), f2bf(v.z), f2bf(v.w) };
    *reinterpret_cast<u16x4*>(dst + off) = o;
  }
}

// ---------------- GEMM: C[M,N] = A[M,K] * B[N,K]^T (m97-style body) --------
__device__ __forceinline__ void gemm_body(const short* __restrict__ A,
                                          const short* __restrict__ B,
                                          short* __restrict__ Cb,
                                          float* __restrict__ Cf,
                                          const float* __restrict__ bias,
                                          int N, int K, int bx, int by) {
  __shared__ short As[128 * 32];
  __shared__ short Bs[128 * 32];
  const int tid  = threadIdx.x;
  const int lane = tid & 63;
  const int wid  = tid >> 6;
  const int wr = wid >> 1, wc = wid & 1;
  const int g = lane >> 4, c = lane & 15;
  const long row0 = (long)by * 128;
  const long col0 = (long)bx * 128;

  const short* gA = A + (row0 + wid * 32 + (lane >> 2)) * (long)K + (lane & 3) * 8;
  const short* gB = B + (col0 + wid * 32 + (lane >> 2)) * (long)K + (lane & 3) * 8;
  short* lA = As + wid * 1024;
  short* lB = Bs + wid * 1024;

  f32x4 acc[4][4];
  const f32x4 z = {0.f, 0.f, 0.f, 0.f};
#pragma unroll
  for (int i = 0; i < 4; i++)
#pragma unroll
    for (int j = 0; j < 4; j++) acc[i][j] = z;

  for (int kt = 0; kt < K; kt += 32) {
    __syncthreads();
    gload_lds16(gA + kt,                lA);
    gload_lds16(gA + kt + 16 * (long)K, lA + 512);
    gload_lds16(gB + kt,                lB);
    gload_lds16(gB + kt + 16 * (long)K, lB + 512);
    __syncthreads();

    bf16x8 af[4], bfr[4];
#pragma unroll
    for (int mf = 0; mf < 4; mf++)
      af[mf] = *reinterpret_cast<const bf16x8*>(As + (wr * 64 + mf * 16 + c) * 32 + g * 8);
#pragma unroll
    for (int nf = 0; nf < 4; nf++)
      bfr[nf] = *reinterpret_cast<const bf16x8*>(Bs + (wc * 64 + nf * 16 + c) * 32 + g * 8);
#pragma unroll
    for (int mf = 0; mf < 4; mf++)
#pragma unroll
      for (int nf = 0; nf < 4; nf++)
        acc[mf][nf] = __builtin_amdgcn_mfma_f32_16x16x32_bf16(af[mf], bfr[nf], acc[mf][nf], 0, 0, 0);
  }

#pragma unroll
  for (int mf = 0; mf < 4; mf++)
#pragma unroll
    for (int nf = 0; nf < 4; nf++)
#pragma unroll
      for (int r = 0; r < 4; r++) {
        const long m = row0 + wr * 64 + mf * 16 + g * 4 + r;
        const long n = col0 + wc * 64 + nf * 16 + c;
        if (Cb) Cb[m * N + n] = (short)f2bf(acc[mf][nf][r]);
        else    Cf[m * N + n] = acc[mf][nf][r] + bias[n];
      }
}

__global__ __launch_bounds__(256) void gemm_qkv_k() {   // grid 768 (24x32)
  const int id = blockIdx.x;
  const int j = id >> 3;
  const int bx = j >> 2;
  const int by = ((id & 7) << 2) | (j & 3);
  gemm_body(g_xb, g_wqkv, g_qkv, nullptr, nullptr, 3 * DMODEL, DMODEL, bx, by);
}
__global__ __launch_bounds__(256) void gemm_out_k(float* __restrict__ out,
                                                  const float* __restrict__ bias) { // grid 256
  const int id = blockIdx.x;
  const int j = id >> 3;
  const int bx = j >> 2;
  const int by = ((id & 7) << 2) | (j & 3);
  gemm_body(g_attno, g_wout, nullptr, out, bias, DMODEL, DMODEL, bx, by);
}

// ---------------- V transpose: g_qkv v-section [b,s,h,d] -> g_vt [bh][d][s] -
// 64x64 tiles via LDS with 16B-slot XOR swizzle (write scalar, read b128).
__global__ __launch_bounds__(256) void transpose_v() {
  __shared__ short T[64 * 64];
  const int tid = threadIdx.x;
  const int st = blockIdx.x, bh = blockIdx.y;
  const int b = bh >> 4, h = bh & 15;
  const int s0 = st * 64;
  const int r = tid >> 2;          // phase1: token row / phase2: d row
  const int q4 = tid & 3;

  const short* src = g_qkv + (size_t)(b * SEQ + s0 + r) * QKVLD + 2048 + h * DHEAD + q4 * 16;
  bf16x8 v0 = *reinterpret_cast<const bf16x8*>(src);
  bf16x8 v1 = *reinterpret_cast<const bf16x8*>(src + 8);
#pragma unroll
  for (int j = 0; j < 8; j++) {
    int d = q4 * 16 + j;
    T[d * 64 + (r ^ ((d & 7) << 3))] = v0[j];
    d = q4 * 16 + 8 + j;
    T[d * 64 + (r ^ ((d & 7) << 3))] = v1[j];
  }
  __syncthreads();
  const int d = r;
  short* dst = g_vt + (size_t)(bh * DHEAD + d) * SEQ + s0 + q4 * 16;
  bf16x8 o0 = *reinterpret_cast<const bf16x8*>(&T[d * 64 + ((q4 * 16)     ^ ((d & 7) << 3))]);
  bf16x8 o1 = *reinterpret_cast<const bf16x8*>(&T[d * 64 + ((q4 * 16 + 8) ^ ((d & 7) << 3))]);
  *reinterpret_cast<bf16x8*>(dst)     = o0;
  *reinterpret_cast<bf16x8*>(dst + 8) = o1;
}

// ---------------- causal flash attention v4 ----------------
// grid 512: block = pair index. bh = id&31, jp = id>>5 (0..15).
// Items: qb = 31-jp (long, 32-jp tiles) then qb = jp (jp+1 tiles) -> 33 tiles
// per block, EVERY block. 4 waves x 16 q-rows. KV tile 64 = qblock -> every
// wave computes every tile (no predicate). K and V^T staged via
// global_load_lds, triple-buffered, counted vmcnt(4), raw s_barrier.
__global__ __launch_bounds__(256, 2) void flash_attn() {
  __shared__ short Kl[3][4096];    // 24 KB [key][d] rows of 128B
  __shared__ short Vl[3][4096];    // 24 KB [d][key] rows of 128B (from g_vt)
  __shared__ short Pl[4][1024];    //  8 KB per-wave P [qrow=c][key]
  const int tid = threadIdx.x;
  const int lane = tid & 63, wid = tid >> 6;
  const int g = (lane >> 4) & 3, c = lane & 15;
  const int id = blockIdx.x;
  const int bh = id & 31;          // id%8 clusters a head's blocks per XCD
  const int jp = id >> 5;          // 0..15
  const int b = bh >> 4, h = bh & 15;
  const short* qbase = g_qkv + (size_t)b * SEQ * QKVLD + h * DHEAD;
  const short* kbase = qbase + 1024;
  const short* vtb   = g_vt + (size_t)bh * DHEAD * SEQ;

  // staging geometry: 2 gloads per operand per wave (8 rows x 128B each);
  // source 16B-chunk pre-swizzled so swizzled b128 reads hit distinct banks.
  const int srow = lane >> 3;                  // 0..7
  const int scol = (lane & 7) ^ srow;          // pre-swizzled slot
  const short* kg0 = kbase + (size_t)(wid * 16 + srow) * QKVLD + scol * 8;
  const short* vg0 = vtb   + (size_t)(wid * 16 + srow) * SEQ   + scol * 8;

  const float QS = 0.18033688011112042f;       // log2(e)/sqrt(64)
  const f32x4 z = {0.f, 0.f, 0.f, 0.f};

  for (int item = 0; item < 2; item++) {
    const int qb = item ? jp : (31 - jp);      // long item first
    const int nt = qb + 1;
    const int qw = qb * 64 + wid * 16;

    // Q B-frags (col=c -> q row qw+c), pre-scaled into exp2 domain
    bf16x8 qf[2];
#pragma unroll
    for (int kc = 0; kc < 2; kc++) {
      bf16x8 raw = *reinterpret_cast<const bf16x8*>(
          qbase + (size_t)(qw + c) * QKVLD + kc * 32 + g * 8);
#pragma unroll
      for (int j = 0; j < 8; j++) raw[j] = (short)f2bf(bf2f(raw[j]) * QS);
      qf[kc] = raw;
    }

    f32x4 oacc[4];
#pragma unroll
    for (int nd = 0; nd < 4; nd++) oacc[nd] = z;
    float mrow = -__builtin_inff(), lrow = 0.f;

    // prologue: stage tiles 0 (and 1)
    gload_lds16(kg0,                        &Kl[0][wid * 1024]);
    gload_lds16(kg0 + (size_t)8 * QKVLD,    &Kl[0][wid * 1024 + 512]);
    gload_lds16(vg0,                        &Vl[0][wid * 1024]);
    gload_lds16(vg0 + (size_t)8 * SEQ,      &Vl[0][wid * 1024 + 512]);
    if (nt > 1) {
      gload_lds16(kg0 + (size_t)64 * QKVLD,       &Kl[1][wid * 1024]);
      gload_lds16(kg0 + (size_t)72 * QKVLD,       &Kl[1][wid * 1024 + 512]);
      gload_lds16(vg0 + 64,                       &Vl[1][wid * 1024]);
      gload_lds16(vg0 + (size_t)8 * SEQ + 64,     &Vl[1][wid * 1024 + 512]);
      asm volatile("s_waitcnt vmcnt(4)" ::: "memory");
    } else {
      asm volatile("s_waitcnt vmcnt(0)" ::: "memory");
    }
    __builtin_amdgcn_sched_barrier(0);
    __builtin_amdgcn_s_barrier();
    asm volatile("" ::: "memory");

    int cur = 0;
    for (int t = 0; t < nt; t++) {
      const bool sl = (t + 2 < nt);
      if (sl) {                                // stage tile t+2
        const int sidx = (cur >= 1) ? cur - 1 : 2;   // (cur+2)%3
        const size_t ko = (size_t)(t + 2) * 64 * QKVLD;
        const size_t vo = (size_t)(t + 2) * 64;
        gload_lds16(kg0 + ko,                     &Kl[sidx][wid * 1024]);
        gload_lds16(kg0 + ko + (size_t)8 * QKVLD, &Kl[sidx][wid * 1024 + 512]);
        gload_lds16(vg0 + vo,                     &Vl[sidx][wid * 1024]);
        gload_lds16(vg0 + vo + (size_t)8 * SEQ,   &Vl[sidx][wid * 1024 + 512]);
      }
      // ---- QK^T swapped: sc[m] = D[key=m*16+g*4+r][q=c] ----
      f32x4 sc[4];
      __builtin_amdgcn_s_setprio(1);
#pragma unroll
      for (int m = 0; m < 4; m++) {
        const short* kr = &Kl[cur][(m * 16 + c) * 64];
        bf16x8 ka0 = *reinterpret_cast<const bf16x8*>(kr + ((g ^ (c & 7)) << 3));
        bf16x8 ka1 = *reinterpret_cast<const bf16x8*>(kr + (((4 + g) ^ (c & 7)) << 3));
        f32x4 s = __builtin_amdgcn_mfma_f32_16x16x32_bf16(ka0, qf[0], z, 0, 0, 0);
        sc[m] = __builtin_amdgcn_mfma_f32_16x16x32_bf16(ka1, qf[1], s, 0, 0, 0);
      }
      __builtin_amdgcn_s_setprio(0);
      if (t == nt - 1) {                       // diagonal tile: causal mask
#pragma unroll
        for (int m = 0; m < 4; m++)
#pragma unroll
          for (int r = 0; r < 4; r++)
            if (m * 16 + g * 4 + r > wid * 16 + c) sc[m][r] = -__builtin_inff();
      }
      // ---- online softmax (row = c), exp2 domain, defer-max THR=8 ----
      f32x4 mm;
#pragma unroll
      for (int r = 0; r < 4; r++)
        mm[r] = fmaxf(fmaxf(sc[0][r], sc[1][r]), fmaxf(sc[2][r], sc[3][r]));
      float tmx = fmaxf(fmaxf(mm[0], mm[1]), fmaxf(mm[2], mm[3]));
      tmx = fmaxf(tmx, __shfl_xor(tmx, 16, 64));
      tmx = fmaxf(tmx, __shfl_xor(tmx, 32, 64));
      if (__any(tmx > mrow + 8.f)) {
        const float mn = fmaxf(mrow, tmx);
        const float al = exp2f(mrow - mn);     // first tile: exp2(-inf)=0
        mrow = mn; lrow *= al;
#pragma unroll
        for (int r = 0; r < 4; r++) {
          const float alr = __shfl(al, g * 4 + r, 64);
#pragma unroll
          for (int nd = 0; nd < 4; nd++) oacc[nd][r] *= alr;
        }
      }
      float rs = 0.f;
#pragma unroll
      for (int m = 0; m < 4; m++) {
        u16x4 pb;
#pragma unroll
        for (int r = 0; r < 4; r++) {
          const float p = exp2f(sc[m][r] - mrow);
          rs += p; pb[r] = f2bf(p);
        }
        *reinterpret_cast<u16x4*>(&Pl[wid][c * 64 + ((m * 16 + g * 4) ^ ((c & 7) << 3))]) = pb;
      }
      rs += __shfl_xor(rs, 16, 64);
      rs += __shfl_xor(rs, 32, 64);
      lrow += rs;
      asm volatile("s_waitcnt lgkmcnt(0)" ::: "memory");   // P visible in-wave
      __builtin_amdgcn_sched_barrier(0);
      // ---- PV: A = P[q=c][key], B = V^T[d][key] ----
      bf16x8 pa0 = *reinterpret_cast<const bf16x8*>(&Pl[wid][c * 64 + ((g * 8)      ^ ((c & 7) << 3))]);
      bf16x8 pa1 = *reinterpret_cast<const bf16x8*>(&Pl[wid][c * 64 + ((32 + g * 8) ^ ((c & 7) << 3))]);
      __builtin_amdgcn_s_setprio(1);
#pragma unroll
      for (int nd = 0; nd < 4; nd++) {
        const short* vr = &Vl[cur][(nd * 16 + c) * 64];
        bf16x8 vf0 = *reinterpret_cast<const bf16x8*>(vr + ((g ^ (c & 7)) << 3));
        bf16x8 vf1 = *reinterpret_cast<const bf16x8*>(vr + (((4 + g) ^ (c & 7)) << 3));
        oacc[nd] = __builtin_amdgcn_mfma_f32_16x16x32_bf16(pa0, vf0, oacc[nd], 0, 0, 0);
        oacc[nd] = __builtin_amdgcn_mfma_f32_16x16x32_bf16(pa1, vf1, oacc[nd], 0, 0, 0);
      }
      __builtin_amdgcn_s_setprio(0);
      // counted drain: retire tile t+1's gloads (keep t+2's 4 in flight)
      if (sl) asm volatile("s_waitcnt vmcnt(4)" ::: "memory");
      else    asm volatile("s_waitcnt vmcnt(0)" ::: "memory");
      asm volatile("s_waitcnt lgkmcnt(0)" ::: "memory");
      __builtin_amdgcn_sched_barrier(0);
      __builtin_amdgcn_s_barrier();
      asm volatile("" ::: "memory");
      cur = (cur == 2) ? 0 : cur + 1;
    }

    // epilogue: O rows qw + g*4+r, cols h*64 + nd*16+c
    const float inv = 1.f / lrow;
#pragma unroll
    for (int r = 0; r < 4; r++) {
      const float linv = __shfl(inv, g * 4 + r, 64);
      const size_t orow = ((size_t)b * SEQ + qw + g * 4 + r) * DMODEL + h * DHEAD;
#pragma unroll
      for (int nd = 0; nd < 4; nd++)
        g_attno[orow + nd * 16 + c] = (short)f2bf(oacc[nd][r] * linv);
    }
  }
}

extern "C" void kernel_launch(void* const* d_in, const int* in_sizes, int n_in,
                              void* d_out, int out_size, void* d_ws, size_t ws_size,
                              hipStream_t stream) {
  (void)in_sizes; (void)n_in; (void)d_ws; (void)ws_size; (void)out_size;
  const float* x    = (const float*)d_in[0];
  const float* Wqkv = (const float*)d_in[1];
  const float* Wout = (const float*)d_in[2];
  const float* bout = (const float*)d_in[3];
  float* out = (float*)d_out;

  cvt3<<<2048, 256, 0, stream>>>(x, Wqkv, Wout);
  gemm_qkv_k<<<768, 256, 0, stream>>>();
  transpose_v<<<dim3(32, 32), 256, 0, stream>>>();
  flash_attn<<<512, 256, 0, stream>>>();
  gemm_out_k<<<256, 256, 0, stream>>>(out, bout);
}